// Round 9
// baseline (452.744 us; speedup 1.0000x reference)
//
#include <hip/hip_runtime.h>

// Trajectron sliding-window LSTM embed:
//   inputs [T=256, B=128, N=4, D=2] f32
//   his LSTM H=32 over n=3; int LSTM H=8 over n=0; window 64 ending at t
//   out[t,b,:] = [h_his | h_int] @ W_out.T + b_out   -> [256,128,2] f32
//
// Round-9: unit-per-lane (R8 mapping) with three fixes.
//   1. Single-wave blocks + __launch_bounds__(64,1): VGPR budget 256+
//      (R8's (256,2) squeezed to 128 and demoted the weights).
//   2. Weights loaded straight from global (L1/L2-served, 19KB hot) into
//      v2f-TYPED arrays: kills R8's 1.47e7 LDS staging bank conflicts
//      (lane-j row stride 128B = all lanes on bank 0) AND the operand
//      marshaling (float4->v2f extraction cost 2 v_movs per pk_fma in R8).
//   3. h exchange read as v2f (uniform ds_read_b64 broadcast, free).
// Lane (c,j): unit j of chain c (2 chains/wave). 4 his gate rows = 128
// floats + int rows = 32 floats resident in VGPRs. No barriers in the loop
// (wave-private LDS h + R2/R8-verified wave fence).

typedef float v2f __attribute__((ext_vector_type(2)));

static __device__ __forceinline__ float fexp2(float x) {
    return __builtin_amdgcn_exp2f(x);
}
static __device__ __forceinline__ float frcp(float x) {
    return __builtin_amdgcn_rcpf(x);
}
static __device__ __forceinline__ void pk_fma(v2f& d, v2f a, v2f b) {
    asm("v_pk_fma_f32 %0, %1, %2, %0" : "+v"(d) : "v"(a), "v"(b));
}

#define LOG2E    1.442695041f
#define TWOLOG2E 2.885390082f

// ws layout (floats) -- identical to rounds 5-8 (correctness-verified):
//   [0,256)     hisX : 2*r+{0,1} = Wih_his[r][:] * s_r
//   [256,384)   hisB : (bih+bhh)[r] * s_r
//   [384,4480)  hisW : r*32+k = Whh_his[r][k] * s_r
//   [4480,4544) intX
//   [4544,4576) intB
//   [4576,4832) intW : r*8+k
// s_r = -log2e for sigmoid rows (i,f,o), -2*log2e for g rows.
__global__ __launch_bounds__(256) void prep_kernel(
    const float* __restrict__ Wih_his, const float* __restrict__ Whh_his,
    const float* __restrict__ bih_his, const float* __restrict__ bhh_his,
    const float* __restrict__ Wih_int, const float* __restrict__ Whh_int,
    const float* __restrict__ bih_int, const float* __restrict__ bhh_int,
    float* __restrict__ ws)
{
    const int i = blockIdx.x * 256 + threadIdx.x;
    if (i < 256) {                      // hisX
        const int r = i >> 1;
        const float s = (r >= 64 && r < 96) ? -TWOLOG2E : -LOG2E;
        ws[i] = Wih_his[i] * s;
    } else if (i < 384) {               // hisB
        const int r = i - 256;
        const float s = (r >= 64 && r < 96) ? -TWOLOG2E : -LOG2E;
        ws[i] = (bih_his[r] + bhh_his[r]) * s;
    } else if (i < 4480) {              // hisW
        const int e = i - 384, r = e >> 5;
        const float s = (r >= 64 && r < 96) ? -TWOLOG2E : -LOG2E;
        ws[i] = Whh_his[e] * s;
    } else if (i < 4544) {              // intX
        const int e = i - 4480, r = e >> 1;
        const float s = (r >= 16 && r < 24) ? -TWOLOG2E : -LOG2E;
        ws[i] = Wih_int[e] * s;
    } else if (i < 4576) {              // intB
        const int r = i - 4544;
        const float s = (r >= 16 && r < 24) ? -TWOLOG2E : -LOG2E;
        ws[i] = (bih_int[r] + bhh_int[r]) * s;
    } else if (i < 4832) {              // intW
        const int e = i - 4576, r = e >> 3;
        const float s = (r >= 16 && r < 24) ? -TWOLOG2E : -LOG2E;
        ws[i] = Whh_int[e] * s;
    }
}

__global__ __launch_bounds__(64, 1) void traj_kernel(
    const float* __restrict__ inp,     // [256][128][4][2]
    const float* __restrict__ ws,      // preprocessed weights (see prep)
    const float* __restrict__ W_out,   // [2][40]
    const float* __restrict__ b_out,   // [2]
    float* __restrict__ out)           // [256][128][2]
{
    __shared__ __align__(16) float hb[2][2][32];  // [buf][chain][unit]
    __shared__ __align__(16) float ib[2][2][8];   // int h

    const int lane = threadIdx.x;
    const int W    = blockIdx.x;                // wave id: chains {2W, 2W+1}
    const int t    = W >> 6;                    // uniform per wave
    const int c    = lane >> 5;                 // chain half
    const int j    = lane & 31;                 // his unit
    const int jj   = j & 7;                     // int unit (x4 redundant)
    const int b    = ((W & 63) << 1) | c;
    const int nsteps = (t >= 63) ? 64 : (t + 1);
    const int tau0   = (t >= 63) ? (t - 63) : 0;

    // ---- own weights global -> VGPRs (v2f-typed: no marshaling) ----
    v2f wh[4][16];            // his rows g*32+j  (128 VGPRs)
    v2f wi[4][4];             // int rows g*8+jj  (32 VGPRs)
    float bh[4], bi[4];
    v2f  wxh[4], wxi[4];
    {
        const v2f* wsW  = reinterpret_cast<const v2f*>(ws + 384);
        const v2f* wsWi = reinterpret_cast<const v2f*>(ws + 4576);
        const v2f* wsX  = reinterpret_cast<const v2f*>(ws);
        const v2f* wsXi = reinterpret_cast<const v2f*>(ws + 4480);
#pragma unroll
        for (int g = 0; g < 4; ++g) {
            const v2f* row = wsW + (g * 32 + j) * 16;
#pragma unroll
            for (int k = 0; k < 16; ++k) wh[g][k] = row[k];
            const v2f* rowi = wsWi + (g * 8 + jj) * 4;
#pragma unroll
            for (int k = 0; k < 4; ++k) wi[g][k] = rowi[k];
            bh[g]  = ws[256 + g * 32 + j];
            bi[g]  = ws[4544 + g * 8 + jj];
            wxh[g] = wsX[g * 32 + j];
            wxi[g] = wsXi[g * 8 + jj];
        }
    }
    // keep the loads above hoisted & resident (asm may write memory)
    asm volatile("" ::: "memory");

    // ---- init h buffers + cell state ----
    hb[0][c][j] = 0.f;
    if (j < 8) ib[0][c][j] = 0.f;
    float cc = 0.f, cci = 0.f;
    float hFin = 0.f, hiFin = 0.f;

    const float* xc = inp + tau0 * 1024 + b * 8;
    float2 xh2 = *reinterpret_cast<const float2*>(xc + 6);   // n=3
    float2 xi2 = *reinterpret_cast<const float2*>(xc);       // n=0
    xc += 1024;

#pragma unroll 1
    for (int s = 0; s < nsteps; ++s) {
        // wave-local fence: prior h writes visible (R2/R8-verified)
        __builtin_amdgcn_wave_barrier();
        asm volatile("s_waitcnt lgkmcnt(0)" ::: "memory");
        __builtin_amdgcn_wave_barrier();

        const int rb = s & 1, wb = rb ^ 1;

        // read chain-c h as v2f (uniform per half-wave: broadcast, free)
        v2f hv[16], iv[4];
        {
            const v2f* hp = reinterpret_cast<const v2f*>(&hb[rb][c][0]);
#pragma unroll
            for (int q = 0; q < 16; ++q) hv[q] = hp[q];
            const v2f* ip = reinterpret_cast<const v2f*>(&ib[rb][c][0]);
#pragma unroll
            for (int q = 0; q < 4; ++q) iv[q] = ip[q];
        }

        float2 nxh = {0.f, 0.f}, nxi = {0.f, 0.f};
        if (s + 1 < nsteps) {                     // wave-uniform branch
            nxh = *reinterpret_cast<const float2*>(xc + 6);
            nxi = *reinterpret_cast<const float2*>(xc);
        }
        xc += 1024;

        const v2f xvh = {xh2.x, xh2.y};
        const v2f xvi = {xi2.x, xi2.y};

        // ---- his: 4 gate dot products, pure register pk_fma ----
        float a[4];
#pragma unroll
        for (int g = 0; g < 4; ++g) {
            v2f acc = {bh[g], 0.f};
            pk_fma(acc, wxh[g], xvh);
#pragma unroll
            for (int k = 0; k < 16; ++k) pk_fma(acc, wh[g][k], hv[k]);
            a[g] = acc.x + acc.y;
        }
        const float si = frcp(1.f + fexp2(a[0]));
        const float sf = frcp(1.f + fexp2(a[1]));
        const float tg = fmaf(2.f, frcp(1.f + fexp2(a[2])), -1.f);
        const float so = frcp(1.f + fexp2(a[3]));
        cc = fmaf(sf, cc, si * tg);
        hFin = so * fmaf(-2.f, frcp(1.f + fexp2(TWOLOG2E * cc)), 1.f);
        hb[wb][c][j] = hFin;     // 64 unique slots: conflict-free b32

        // ---- int: unit jj (redundant x4 across j-groups) ----
        float ai[4];
#pragma unroll
        for (int g = 0; g < 4; ++g) {
            v2f acc = {bi[g], 0.f};
            pk_fma(acc, wxi[g], xvi);
#pragma unroll
            for (int k = 0; k < 4; ++k) pk_fma(acc, wi[g][k], iv[k]);
            ai[g] = acc.x + acc.y;
        }
        const float sii = frcp(1.f + fexp2(ai[0]));
        const float sfi = frcp(1.f + fexp2(ai[1]));
        const float tgi = fmaf(2.f, frcp(1.f + fexp2(ai[2])), -1.f);
        const float soi = frcp(1.f + fexp2(ai[3]));
        cci = fmaf(sfi, cci, sii * tgi);
        hiFin = soi * fmaf(-2.f, frcp(1.f + fexp2(TWOLOG2E * cci)), 1.f);
        if (j < 8) ib[wb][c][j] = hiFin;

        xh2 = nxh; xi2 = nxi;
    }

    // ---- projection: lane contributes its unit(s); reduce over 32 ----
    float e0 = W_out[j] * hFin;
    float e1 = W_out[40 + j] * hFin;
    if (j < 8) {
        e0 = fmaf(W_out[32 + j], hiFin, e0);
        e1 = fmaf(W_out[72 + j], hiFin, e1);
    }
#pragma unroll
    for (int m = 16; m >= 1; m >>= 1) {
        e0 += __shfl_xor(e0, m);
        e1 += __shfl_xor(e1, m);
    }
    if (j == 0) {
        float2 o;
        o.x = e0 + b_out[0];
        o.y = e1 + b_out[1];
        reinterpret_cast<float2*>(out)[t * 128 + b] = o;
    }
}

extern "C" void kernel_launch(void* const* d_in, const int* in_sizes, int n_in,
                              void* d_out, int out_size, void* d_ws, size_t ws_size,
                              hipStream_t stream) {
    const float* inp     = (const float*)d_in[0];
    const float* Wih_his = (const float*)d_in[1];
    const float* Whh_his = (const float*)d_in[2];
    const float* bih_his = (const float*)d_in[3];
    const float* bhh_his = (const float*)d_in[4];
    const float* Wih_int = (const float*)d_in[5];
    const float* Whh_int = (const float*)d_in[6];
    const float* bih_int = (const float*)d_in[7];
    const float* bhh_int = (const float*)d_in[8];
    const float* W_out   = (const float*)d_in[9];
    const float* b_out   = (const float*)d_in[10];
    float* out = (float*)d_out;
    float* ws  = (float*)d_ws;

    // pre-pass: fold log2e scales + bias merge into ws (4832 floats)
    prep_kernel<<<dim3(19), dim3(256), 0, stream>>>(
        Wih_his, Whh_his, bih_his, bhh_his,
        Wih_int, Whh_int, bih_int, bhh_int, ws);

    // 16384 single-wave blocks; wave = 2 chains (unit-per-lane).
    traj_kernel<<<dim3(16384), dim3(64), 0, stream>>>(
        inp, ws, W_out, b_out, out);
}

// Round 10
// 419.657 us; speedup vs baseline: 1.0788x; 1.0788x over previous
//
#include <hip/hip_runtime.h>

// Trajectron sliding-window LSTM embed:
//   inputs [T=256, B=128, N=4, D=2] f32
//   his LSTM H=32 over n=3; int LSTM H=8 over n=0; window 64 ending at t
//   out[t,b,:] = [h_his | h_int] @ W_out.T + b_out   -> [256,128,2] f32
//
// Round-10: unit-per-lane (R8/R9 mapping) with the weight-residency problem
// actually fixed. R9 evidence: VGPR_Count=128 under __launch_bounds__(64,1)
// -> the scheduler remats weight loads into the loop targeting 4 waves/EU
// (128 = 512/4). Fixes:
//   1. amdgpu_waves_per_eu(2,2): min=2 caps VGPR at 256 (need ~227), max=2
//      removes the occupancy incentive to remat below that. Volatile "+v"
//      pins per weight register make remat structurally impossible.
//   2. Int LSTM: gate-ROW-per-lane (32 rows = 32 lanes/chain, 7 VGPRs,
//      4 ds_bpermute to reassemble) instead of unit-per-lane redundant x4
//      (40 VGPRs, 44 instr) -- saves ~28 instr/step + 33 VGPRs.
//   3. 2 waves/SIMD TLP covers the lgkm fence + DS latency.
// No barriers in the loop (wave-private LDS h + R2/R8/R9-verified fence).

typedef float v2f __attribute__((ext_vector_type(2)));

static __device__ __forceinline__ float fexp2(float x) {
    return __builtin_amdgcn_exp2f(x);
}
static __device__ __forceinline__ float frcp(float x) {
    return __builtin_amdgcn_rcpf(x);
}
static __device__ __forceinline__ void pk_fma(v2f& d, v2f a, v2f b) {
    asm("v_pk_fma_f32 %0, %1, %2, %0" : "+v"(d) : "v"(a), "v"(b));
}

#define LOG2E    1.442695041f
#define TWOLOG2E 2.885390082f

// ws layout (floats) -- identical to rounds 5-9 (correctness-verified):
//   [0,256)     hisX : 2*r+{0,1} = Wih_his[r][:] * s_r
//   [256,384)   hisB : (bih+bhh)[r] * s_r
//   [384,4480)  hisW : r*32+k = Whh_his[r][k] * s_r
//   [4480,4544) intX
//   [4544,4576) intB
//   [4576,4832) intW : r*8+k
// s_r = -log2e for sigmoid rows (i,f,o), -2*log2e for g rows.
__global__ __launch_bounds__(256) void prep_kernel(
    const float* __restrict__ Wih_his, const float* __restrict__ Whh_his,
    const float* __restrict__ bih_his, const float* __restrict__ bhh_his,
    const float* __restrict__ Wih_int, const float* __restrict__ Whh_int,
    const float* __restrict__ bih_int, const float* __restrict__ bhh_int,
    float* __restrict__ ws)
{
    const int i = blockIdx.x * 256 + threadIdx.x;
    if (i < 256) {                      // hisX
        const int r = i >> 1;
        const float s = (r >= 64 && r < 96) ? -TWOLOG2E : -LOG2E;
        ws[i] = Wih_his[i] * s;
    } else if (i < 384) {               // hisB
        const int r = i - 256;
        const float s = (r >= 64 && r < 96) ? -TWOLOG2E : -LOG2E;
        ws[i] = (bih_his[r] + bhh_his[r]) * s;
    } else if (i < 4480) {              // hisW
        const int e = i - 384, r = e >> 5;
        const float s = (r >= 64 && r < 96) ? -TWOLOG2E : -LOG2E;
        ws[i] = Whh_his[e] * s;
    } else if (i < 4544) {              // intX
        const int e = i - 4480, r = e >> 1;
        const float s = (r >= 16 && r < 24) ? -TWOLOG2E : -LOG2E;
        ws[i] = Wih_int[e] * s;
    } else if (i < 4576) {              // intB
        const int r = i - 4544;
        const float s = (r >= 16 && r < 24) ? -TWOLOG2E : -LOG2E;
        ws[i] = (bih_int[r] + bhh_int[r]) * s;
    } else if (i < 4832) {              // intW
        const int e = i - 4576, r = e >> 3;
        const float s = (r >= 16 && r < 24) ? -TWOLOG2E : -LOG2E;
        ws[i] = Whh_int[e] * s;
    }
}

__global__ __launch_bounds__(64)
__attribute__((amdgpu_waves_per_eu(2, 2)))
void traj_kernel(
    const float* __restrict__ inp,     // [256][128][4][2]
    const float* __restrict__ ws,      // preprocessed weights (see prep)
    const float* __restrict__ W_out,   // [2][40]
    const float* __restrict__ b_out,   // [2]
    float* __restrict__ out)           // [256][128][2]
{
    __shared__ __align__(16) float hb[2][2][32];  // [buf][chain][unit]
    __shared__ __align__(16) float ib[2][2][8];   // int h

    const int lane = threadIdx.x;
    const int W    = blockIdx.x;                // wave id: chains {2W, 2W+1}
    const int t    = W >> 6;                    // uniform per wave
    const int c    = lane >> 5;                 // chain half
    const int j    = lane & 31;                 // his unit / int gate-row
    const int b    = ((W & 63) << 1) | c;
    const int nsteps = (t >= 63) ? 64 : (t + 1);
    const int tau0   = (t >= 63) ? (t - 63) : 0;

    // ---- own weights global -> VGPRs, once ----
    v2f wh[4][16];            // his rows g*32+j      (128 VGPRs)
    v2f wiR[4];               // int gate-row j       (8 VGPRs)
    float bh[4], biR;
    v2f  wxh[4], wxiR;
    {
        const v2f* wsW = reinterpret_cast<const v2f*>(ws + 384);
        const v2f* wsX = reinterpret_cast<const v2f*>(ws);
#pragma unroll
        for (int g = 0; g < 4; ++g) {
            const v2f* row = wsW + (g * 32 + j) * 16;
#pragma unroll
            for (int k = 0; k < 16; ++k) wh[g][k] = row[k];
            bh[g]  = ws[256 + g * 32 + j];
            wxh[g] = wsX[g * 32 + j];
        }
        const v2f* rowi = reinterpret_cast<const v2f*>(ws + 4576) + j * 4;
#pragma unroll
        for (int k = 0; k < 4; ++k) wiR[k] = rowi[k];
        biR  = ws[4544 + j];
        wxiR = reinterpret_cast<const v2f*>(ws + 4480)[j];
    }
    // volatile pins: remat of these loads is now impossible (asm cannot be
    // re-executed or sunk into the loop); budget 256 > need ~227 -> no spill
#pragma unroll
    for (int g = 0; g < 4; ++g) {
#pragma unroll
        for (int k = 0; k < 16; ++k) asm volatile("" : "+v"(wh[g][k]));
        asm volatile("" : "+v"(wxh[g]), "+v"(bh[g]));
    }
#pragma unroll
    for (int k = 0; k < 4; ++k) asm volatile("" : "+v"(wiR[k]));
    asm volatile("" : "+v"(wxiR), "+v"(biR));

    // int gate-row j activation type: g-rows are 16..23 (tanh)
    const bool isG = (j >= 16) && (j < 24);
    // bpermute source lanes for int unit u = j&7 (byte addresses)
    const int ubase = ((lane & 32) | (j & 7)) << 2;

    // ---- init h buffers + cell state ----
    hb[0][c][j] = 0.f;
    if (j < 8) ib[0][c][j] = 0.f;
    float cc = 0.f, cci = 0.f;
    float hFin = 0.f, hiFin = 0.f;

    const float* xc = inp + tau0 * 1024 + b * 8;
    float2 xh2 = *reinterpret_cast<const float2*>(xc + 6);   // n=3
    float2 xi2 = *reinterpret_cast<const float2*>(xc);       // n=0
    xc += 1024;

#pragma unroll 1
    for (int s = 0; s < nsteps; ++s) {
        // wave-local fence: prior h writes visible (R2/R8/R9-verified)
        __builtin_amdgcn_wave_barrier();
        asm volatile("s_waitcnt lgkmcnt(0)" ::: "memory");
        __builtin_amdgcn_wave_barrier();

        const int rb = s & 1, wb = rb ^ 1;

        // read chain-c h as v2f (uniform per half-wave: broadcast, free)
        v2f hv[16], iv[4];
        {
            const v2f* hp = reinterpret_cast<const v2f*>(&hb[rb][c][0]);
#pragma unroll
            for (int q = 0; q < 16; ++q) hv[q] = hp[q];
            const v2f* ip = reinterpret_cast<const v2f*>(&ib[rb][c][0]);
#pragma unroll
            for (int q = 0; q < 4; ++q) iv[q] = ip[q];
        }

        float2 nxh = {0.f, 0.f}, nxi = {0.f, 0.f};
        if (s + 1 < nsteps) {                     // wave-uniform branch
            nxh = *reinterpret_cast<const float2*>(xc + 6);
            nxi = *reinterpret_cast<const float2*>(xc);
        }
        xc += 1024;

        const v2f xvh = {xh2.x, xh2.y};
        const v2f xvi = {xi2.x, xi2.y};

        // ---- his: 4 gate dot products, pure register pk_fma ----
        float a[4];
#pragma unroll
        for (int g = 0; g < 4; ++g) {
            v2f acc = {bh[g], 0.f};
            pk_fma(acc, wxh[g], xvh);
#pragma unroll
            for (int k = 0; k < 16; ++k) pk_fma(acc, wh[g][k], hv[k]);
            a[g] = acc.x + acc.y;
        }
        const float si = frcp(1.f + fexp2(a[0]));
        const float sf = frcp(1.f + fexp2(a[1]));
        const float tg = fmaf(2.f, frcp(1.f + fexp2(a[2])), -1.f);
        const float so = frcp(1.f + fexp2(a[3]));
        cc = fmaf(sf, cc, si * tg);
        hFin = so * fmaf(-2.f, frcp(1.f + fexp2(TWOLOG2E * cc)), 1.f);
        hb[wb][c][j] = hFin;     // 64 unique slots: conflict-free b32

        // ---- int: gate-row j, then reassemble unit j&7 via bpermute ----
        {
            v2f acc = {biR, 0.f};
            pk_fma(acc, wxiR, xvi);
#pragma unroll
            for (int k = 0; k < 4; ++k) pk_fma(acc, wiR[k], iv[k]);
            const float av = acc.x + acc.y;
            const float r  = frcp(1.f + fexp2(av));
            const float actv = isG ? fmaf(2.f, r, -1.f) : r;

            const float sii = __builtin_amdgcn_ds_bpermute(ubase,        __float_as_int(actv)) ?
                  0.f : 0.f;  // placeholder avoided below
            (void)sii;
            const float gi = __int_as_float(__builtin_amdgcn_ds_bpermute(ubase,       __float_as_int(actv)));
            const float gf = __int_as_float(__builtin_amdgcn_ds_bpermute(ubase + 32,  __float_as_int(actv)));
            const float gg = __int_as_float(__builtin_amdgcn_ds_bpermute(ubase + 64,  __float_as_int(actv)));
            const float go = __int_as_float(__builtin_amdgcn_ds_bpermute(ubase + 96,  __float_as_int(actv)));

            cci = fmaf(gf, cci, gi * gg);
            hiFin = go * fmaf(-2.f, frcp(1.f + fexp2(TWOLOG2E * cci)), 1.f);
            if (j < 8) ib[wb][c][j] = hiFin;
        }

        xh2 = nxh; xi2 = nxi;
    }

    // ---- projection: lane contributes its unit(s); reduce over 32 ----
    float e0 = W_out[j] * hFin;
    float e1 = W_out[40 + j] * hFin;
    if (j < 8) {
        e0 = fmaf(W_out[32 + j], hiFin, e0);
        e1 = fmaf(W_out[72 + j], hiFin, e1);
    }
#pragma unroll
    for (int m = 16; m >= 1; m >>= 1) {
        e0 += __shfl_xor(e0, m);
        e1 += __shfl_xor(e1, m);
    }
    if (j == 0) {
        float2 o;
        o.x = e0 + b_out[0];
        o.y = e1 + b_out[1];
        reinterpret_cast<float2*>(out)[t * 128 + b] = o;
    }
}

extern "C" void kernel_launch(void* const* d_in, const int* in_sizes, int n_in,
                              void* d_out, int out_size, void* d_ws, size_t ws_size,
                              hipStream_t stream) {
    const float* inp     = (const float*)d_in[0];
    const float* Wih_his = (const float*)d_in[1];
    const float* Whh_his = (const float*)d_in[2];
    const float* bih_his = (const float*)d_in[3];
    const float* bhh_his = (const float*)d_in[4];
    const float* Wih_int = (const float*)d_in[5];
    const float* Whh_int = (const float*)d_in[6];
    const float* bih_int = (const float*)d_in[7];
    const float* bhh_int = (const float*)d_in[8];
    const float* W_out   = (const float*)d_in[9];
    const float* b_out   = (const float*)d_in[10];
    float* out = (float*)d_out;
    float* ws  = (float*)d_ws;

    // pre-pass: fold log2e scales + bias merge into ws (4832 floats)
    prep_kernel<<<dim3(19), dim3(256), 0, stream>>>(
        Wih_his, Whh_his, bih_his, bhh_his,
        Wih_int, Whh_int, bih_int, bhh_int, ws);

    // 16384 single-wave blocks; wave = 2 chains (unit-per-lane his,
    // gate-row-per-lane int); target 2 waves/SIMD resident.
    traj_kernel<<<dim3(16384), dim3(64), 0, stream>>>(
        inp, ws, W_out, b_out, out);
}

// Round 11
// 371.343 us; speedup vs baseline: 1.2192x; 1.1301x over previous
//
#include <hip/hip_runtime.h>

// Trajectron sliding-window LSTM embed:
//   inputs [T=256, B=128, N=4, D=2] f32
//   his LSTM H=32 over n=3; int LSTM H=8 over n=0; window 64 ending at t
//   out[t,b,:] = [h_his | h_int] @ W_out.T + b_out   -> [256,128,2] f32
//
// Round-11: design INSIDE the 128-VGPR envelope (R8-R10 lesson: any mapping
// needing >128 weight VGPRs gets remat'ed by the allocator, period).
//   Kernel A (his): one wave per chain; lane p*32+j owns 2 gate rows
//   (p0: i,f / p1: g,o) = 64 weight floats = 32 VGPR pairs. h[32] exchanged
//   via wave-private LDS: 8 uniform-address ds_read_b128 per step (vs R10's
//   26 DS ops -- R10 was LDS-pipe bound). Gate exchange: 2 shfl_xor(32).
//   c,h computed redundantly on both halves (bit-identical) -> unconditional
//   same-value h write. ~82 wave-inst/step, ~124 VGPRs -> 4 waves/EU with
//   weights RESIDENT (allocator's own target satisfied, no remat incentive).
//   Kernel B (int): 8 chains/wave unit-per-lane, writes the int projection
//   contribution to d_ws (~13us); A adds it in the epilogue.

typedef float v2f __attribute__((ext_vector_type(2)));
typedef float v4f __attribute__((ext_vector_type(4)));

static __device__ __forceinline__ float fexp2(float x) {
    return __builtin_amdgcn_exp2f(x);
}
static __device__ __forceinline__ float frcp(float x) {
    return __builtin_amdgcn_rcpf(x);
}
static __device__ __forceinline__ void pk_fma(v2f& d, v2f a, v2f b) {
    asm("v_pk_fma_f32 %0, %1, %2, %0" : "+v"(d) : "v"(a), "v"(b));
}
static __device__ __forceinline__ v2f loh(v4f v) {
    return __builtin_shufflevector(v, v, 0, 1);   // subregister, no movs
}
static __device__ __forceinline__ v2f hih(v4f v) {
    return __builtin_shufflevector(v, v, 2, 3);
}

#define LOG2E    1.442695041f
#define TWOLOG2E 2.885390082f

// ws layout (floats) -- identical to rounds 5-10 (correctness-verified):
//   [0,256)     hisX   [256,384) hisB   [384,4480) hisW (r*32+k)
//   [4480,4544) intX   [4544,4576) intB [4576,4832) intW (r*8+k)
//   [8192, 8192+65536) eInt: per-chain int contribution float2[32768]
// s_r = -log2e for sigmoid rows (i,f,o), -2*log2e for g rows.
__global__ __launch_bounds__(256) void prep_kernel(
    const float* __restrict__ Wih_his, const float* __restrict__ Whh_his,
    const float* __restrict__ bih_his, const float* __restrict__ bhh_his,
    const float* __restrict__ Wih_int, const float* __restrict__ Whh_int,
    const float* __restrict__ bih_int, const float* __restrict__ bhh_int,
    float* __restrict__ ws)
{
    const int i = blockIdx.x * 256 + threadIdx.x;
    if (i < 256) {                      // hisX
        const int r = i >> 1;
        const float s = (r >= 64 && r < 96) ? -TWOLOG2E : -LOG2E;
        ws[i] = Wih_his[i] * s;
    } else if (i < 384) {               // hisB
        const int r = i - 256;
        const float s = (r >= 64 && r < 96) ? -TWOLOG2E : -LOG2E;
        ws[i] = (bih_his[r] + bhh_his[r]) * s;
    } else if (i < 4480) {              // hisW
        const int e = i - 384, r = e >> 5;
        const float s = (r >= 64 && r < 96) ? -TWOLOG2E : -LOG2E;
        ws[i] = Whh_his[e] * s;
    } else if (i < 4544) {              // intX
        const int e = i - 4480, r = e >> 1;
        const float s = (r >= 16 && r < 24) ? -TWOLOG2E : -LOG2E;
        ws[i] = Wih_int[e] * s;
    } else if (i < 4576) {              // intB
        const int r = i - 4544;
        const float s = (r >= 16 && r < 24) ? -TWOLOG2E : -LOG2E;
        ws[i] = (bih_int[r] + bhh_int[r]) * s;
    } else if (i < 4832) {              // intW
        const int e = i - 4576, r = e >> 3;
        const float s = (r >= 16 && r < 24) ? -TWOLOG2E : -LOG2E;
        ws[i] = Whh_int[e] * s;
    }
}

// ---------- Kernel B: int LSTM, 8 chains per wave, unit-per-lane ----------
__global__ __launch_bounds__(64) void int_kernel(
    const float* __restrict__ inp,     // [256][128][4][2]
    const float* __restrict__ ws,
    const float* __restrict__ W_out,   // [2][40]
    float* __restrict__ eInt)          // [32768] float2 region in ws
{
    __shared__ __align__(16) float ib[2][8][8];   // [buf][chain][unit]

    const int lane = threadIdx.x;
    const int W    = blockIdx.x;                 // 0..4095
    const int t    = W >> 4;                     // uniform per wave
    const int g    = lane >> 3;                  // chain in wave
    const int u    = lane & 7;                   // unit
    const int b    = ((W & 15) << 3) | g;
    const int nsteps = (t >= 63) ? 64 : (t + 1);
    const int tau0   = (t >= 63) ? (t - 63) : 0;

    // rows {u, 8+u, 16+u, 24+u}: 32 floats in VGPRs
    v2f wi[4][4], wxi[4];
    float bi[4];
    {
        const v2f* wsWi = reinterpret_cast<const v2f*>(ws + 4576);
        const v2f* wsXi = reinterpret_cast<const v2f*>(ws + 4480);
#pragma unroll
        for (int q = 0; q < 4; ++q) {
            const v2f* row = wsWi + (q * 8 + u) * 4;
#pragma unroll
            for (int k = 0; k < 4; ++k) wi[q][k] = row[k];
            bi[q]  = ws[4544 + q * 8 + u];
            wxi[q] = wsXi[q * 8 + u];
        }
    }

    ib[0][g][u] = 0.f;
    float cc = 0.f, h = 0.f;

    const float* xc = inp + tau0 * 1024 + b * 8;   // n=0
    float2 xv2 = *reinterpret_cast<const float2*>(xc);
    xc += 1024;

#pragma unroll 1
    for (int s = 0; s < nsteps; ++s) {
        __builtin_amdgcn_wave_barrier();
        asm volatile("s_waitcnt lgkmcnt(0)" ::: "memory");
        __builtin_amdgcn_wave_barrier();

        const int rb = s & 1, wb = rb ^ 1;
        const v4f* ip = reinterpret_cast<const v4f*>(&ib[rb][g][0]);
        const v4f i0 = ip[0], i1 = ip[1];

        float2 nx = {0.f, 0.f};
        if (s + 1 < nsteps) nx = *reinterpret_cast<const float2*>(xc);
        xc += 1024;
        const v2f xv = {xv2.x, xv2.y};

        float a[4];
#pragma unroll
        for (int q = 0; q < 4; ++q) {
            v2f acc = {bi[q], 0.f};
            pk_fma(acc, wxi[q], xv);
            pk_fma(acc, wi[q][0], loh(i0));
            pk_fma(acc, wi[q][1], hih(i0));
            pk_fma(acc, wi[q][2], loh(i1));
            pk_fma(acc, wi[q][3], hih(i1));
            a[q] = acc.x + acc.y;
        }
        const float si = frcp(1.f + fexp2(a[0]));
        const float sf = frcp(1.f + fexp2(a[1]));
        const float tg = fmaf(2.f, frcp(1.f + fexp2(a[2])), -1.f);
        const float so = frcp(1.f + fexp2(a[3]));
        cc = fmaf(sf, cc, si * tg);
        h = so * fmaf(-2.f, frcp(1.f + fexp2(TWOLOG2E * cc)), 1.f);
        ib[wb][g][u] = h;

        xv2 = nx;
    }

    // projection contribution of int units; reduce over the 8 unit lanes
    float e0 = W_out[32 + u] * h;
    float e1 = W_out[72 + u] * h;
#pragma unroll
    for (int m = 4; m >= 1; m >>= 1) {
        e0 += __shfl_xor(e0, m);
        e1 += __shfl_xor(e1, m);
    }
    if (u == 0) {
        float2* ep = reinterpret_cast<float2*>(eInt);
        float2 o; o.x = e0; o.y = e1;
        ep[t * 128 + b] = o;
    }
}

// ---------- Kernel A: his LSTM, one wave per chain, 2 rows per lane -------
__global__ __launch_bounds__(64) void his_kernel(
    const float* __restrict__ inp,     // [256][128][4][2]
    const float* __restrict__ ws,
    const float* __restrict__ W_out,   // [2][40]
    const float* __restrict__ b_out,   // [2]
    const float* __restrict__ eInt,    // float2[32768] (from int_kernel)
    float* __restrict__ out)           // [256][128][2]
{
    __shared__ __align__(16) float hb[2][32];    // [buf][unit], wave-private

    const int lane = threadIdx.x;
    const int W    = blockIdx.x;                 // chain id = t*128+b
    const int t    = W >> 7;
    const int b    = W & 127;
    const int j    = lane & 31;
    const int p    = lane >> 5;                  // p0: i,f rows; p1: g,o rows
    const int nsteps = (t >= 63) ? 64 : (t + 1);
    const int tau0   = (t >= 63) ? (t - 63) : 0;

    const int rA = p * 64 + j;                   // i (p0) / g (p1)
    const int rB = rA + 32;                      // f (p0) / o (p1)

    // 2 gate rows = 64 floats = 32 VGPR pairs (fits the 128-VGPR envelope)
    v2f wA[16], wB[16], wxA, wxB;
    float bA, bB;
    {
        const v2f* wsW = reinterpret_cast<const v2f*>(ws + 384);
        const v2f* a2 = wsW + rA * 16;
        const v2f* b2 = wsW + rB * 16;
#pragma unroll
        for (int k = 0; k < 16; ++k) { wA[k] = a2[k]; wB[k] = b2[k]; }
        bA  = ws[256 + rA];
        bB  = ws[256 + rB];
        wxA = reinterpret_cast<const v2f*>(ws)[rA];
        wxB = reinterpret_cast<const v2f*>(ws)[rB];
    }

    // vA = p ? tanh-form : sig-form, via fma(scl, r, off)
    const float sclA = p ? 2.f : 1.f;
    const float offA = p ? -1.f : 0.f;

    hb[0][j] = 0.f;            // both halves write same value: benign
    float cc = 0.f, h = 0.f;

    const float* xc = inp + tau0 * 1024 + b * 8 + 6;   // n=3, wave-uniform
    float2 xv2 = *reinterpret_cast<const float2*>(xc);
    xc += 1024;

#pragma unroll 1
    for (int s = 0; s < nsteps; ++s) {
        __builtin_amdgcn_wave_barrier();
        asm volatile("s_waitcnt lgkmcnt(0)" ::: "memory");
        __builtin_amdgcn_wave_barrier();

        const int rb = s & 1, wb = rb ^ 1;

        // h[32]: 8 uniform-address b128 reads (hardware broadcast)
        const v4f* hp = reinterpret_cast<const v4f*>(&hb[rb][0]);
        v4f hq[8];
#pragma unroll
        for (int q = 0; q < 8; ++q) hq[q] = hp[q];

        float2 nx = {0.f, 0.f};
        if (s + 1 < nsteps) nx = *reinterpret_cast<const float2*>(xc);
        xc += 1024;
        const v2f xv = {xv2.x, xv2.y};

        v2f aA = {bA, 0.f}, aB = {bB, 0.f};
        pk_fma(aA, wxA, xv);
        pk_fma(aB, wxB, xv);
#pragma unroll
        for (int q = 0; q < 8; ++q) {
            const v2f hl = loh(hq[q]), hh = hih(hq[q]);
            pk_fma(aA, wA[2 * q],     hl);
            pk_fma(aA, wA[2 * q + 1], hh);
            pk_fma(aB, wB[2 * q],     hl);
            pk_fma(aB, wB[2 * q + 1], hh);
        }
        const float fA = aA.x + aA.y;
        const float fB = aB.x + aB.y;

        const float rAe = frcp(1.f + fexp2(fA));
        const float vA  = fmaf(sclA, rAe, offA);   // p0: sig(i) | p1: tanh(g)
        const float vB  = frcp(1.f + fexp2(fB));   // p0: sig(f) | p1: sig(o)

        const float oA = __shfl_xor(vA, 32);
        const float oB = __shfl_xor(vB, 32);

        const float gi = p ? oA : vA;
        const float gf = p ? oB : vB;
        const float gg = p ? vA : oA;
        const float go = p ? vB : oB;

        cc = fmaf(gf, cc, gi * gg);
        h = go * fmaf(-2.f, frcp(1.f + fexp2(TWOLOG2E * cc)), 1.f);

        hb[wb][j] = h;          // both halves write identical value

        xv2 = nx;
    }

    // ---- projection: reduce over the 32 unit lanes (halves mirrored) ----
    float e0 = W_out[j] * h;
    float e1 = W_out[40 + j] * h;
#pragma unroll
    for (int m = 16; m >= 1; m >>= 1) {
        e0 += __shfl_xor(e0, m);
        e1 += __shfl_xor(e1, m);
    }
    if (lane == 0) {
        const float2 ei = reinterpret_cast<const float2*>(eInt)[W];
        float2 o;
        o.x = e0 + ei.x + b_out[0];
        o.y = e1 + ei.y + b_out[1];
        reinterpret_cast<float2*>(out)[W] = o;
    }
}

extern "C" void kernel_launch(void* const* d_in, const int* in_sizes, int n_in,
                              void* d_out, int out_size, void* d_ws, size_t ws_size,
                              hipStream_t stream) {
    const float* inp     = (const float*)d_in[0];
    const float* Wih_his = (const float*)d_in[1];
    const float* Whh_his = (const float*)d_in[2];
    const float* bih_his = (const float*)d_in[3];
    const float* bhh_his = (const float*)d_in[4];
    const float* Wih_int = (const float*)d_in[5];
    const float* Whh_int = (const float*)d_in[6];
    const float* bih_int = (const float*)d_in[7];
    const float* bhh_int = (const float*)d_in[8];
    const float* W_out   = (const float*)d_in[9];
    const float* b_out   = (const float*)d_in[10];
    float* out  = (float*)d_out;
    float* ws   = (float*)d_ws;
    float* eInt = ws + 8192;           // float2[32768] = 256 KB

    // pre-pass: fold log2e scales + bias merge into ws (4832 floats)
    prep_kernel<<<dim3(19), dim3(256), 0, stream>>>(
        Wih_his, Whh_his, bih_his, bhh_his,
        Wih_int, Whh_int, bih_int, bhh_int, ws);

    // int LSTM: 4096 waves, 8 chains each -> eInt contributions
    int_kernel<<<dim3(4096), dim3(64), 0, stream>>>(inp, ws, W_out, eInt);

    // his LSTM: 32768 single-wave blocks, 1 chain per wave
    his_kernel<<<dim3(32768), dim3(64), 0, stream>>>(
        inp, ws, W_out, b_out, eInt, out);
}

// Round 12
// 209.780 us; speedup vs baseline: 2.1582x; 1.7702x over previous
//
#include <hip/hip_runtime.h>

// Trajectron sliding-window LSTM embed:
//   inputs [T=256, B=128, N=4, D=2] f32
//   his LSTM H=32 over n=3; int LSTM H=8 over n=0; window 64 ending at t
//   out[t,b,:] = [h_his | h_int] @ W_out.T + b_out   -> [256,128,2] f32
//
// Round-12: the his LSTM recurrence is a batched GEMM per step:
//   G[16 chains x 128 gate-rows] = H[16x32] @ Whh^T  ->  one wave,
//   8 x mfma_f32_16x16x32_f16 (K=32 = H exactly). Weights = 8 B-frags =
//   32 VGPRs loaded once (small enough that the remat heuristic that ate
//   rounds 8-11 has nothing to chew on). VALU now does only the x-part
//   C-init + activations. B rows are PERMUTED in prep so each lane's D regs
//   hold all 4 gates of units {2n, 2n+1} for its 4 chains (C/D layout:
//   col=lane&15, row=quad*4+reg — m89/m91-verified); activations are
//   lane-local, c-state in regs. New h: fp16-pack -> 4 ds_write_b32 ->
//   wave fence -> 1 ds_read_b128 = A-frag (A layout: m=lane&15, k=quad*8+j,
//   m120-verified). fp16 keeps absmax ~3e-4 (threshold 2.75e-3).
// Int LSTM: R11's kernel unchanged (writes eInt; his adds it in epilogue).

typedef float v2f __attribute__((ext_vector_type(2)));
typedef float v4f __attribute__((ext_vector_type(4)));
typedef _Float16 h8v __attribute__((ext_vector_type(8)));

static __device__ __forceinline__ float fexp2(float x) {
    return __builtin_amdgcn_exp2f(x);
}
static __device__ __forceinline__ float frcp(float x) {
    return __builtin_amdgcn_rcpf(x);
}
static __device__ __forceinline__ void pk_fma(v2f& d, v2f a, v2f b) {
    asm("v_pk_fma_f32 %0, %1, %2, %0" : "+v"(d) : "v"(a), "v"(b));
}
static __device__ __forceinline__ v2f loh(v4f v) {
    return __builtin_shufflevector(v, v, 0, 1);
}
static __device__ __forceinline__ v2f hih(v4f v) {
    return __builtin_shufflevector(v, v, 2, 3);
}
static __device__ __forceinline__ unsigned short f2h(float f) {
    _Float16 h = (_Float16)f;
    unsigned short u;
    __builtin_memcpy(&u, &h, 2);
    return u;
}

#define LOG2E    1.442695041f
#define TWOLOG2E 2.885390082f

// ws layout:
//   [0,256) hisX  [256,384) hisB  [384,4480) hisW      (legacy, unused)
//   [4480,4544) intX [4544,4576) intB [4576,4832) intW (int kernel)
//   [5120,5248) hisBP : fp32 permuted-prescaled bias, index p
//   [5376,5632) hisXP : fp32 permuted-prescaled Wih, 2p+{0,1}
//   ushort idx [11776, 15872): hisWH fp16 permuted-prescaled Whh [128][32]
//   [8192, +65536) eInt : per-chain int contribution float2[32768]
// permutation p = T*16+n -> orig row r = (T>>1)*32 + 2n + (T&1)
// scale s_r = -log2e (i,f,o rows) / -2log2e (g rows)
__global__ __launch_bounds__(256) void prep_kernel(
    const float* __restrict__ Wih_his, const float* __restrict__ Whh_his,
    const float* __restrict__ bih_his, const float* __restrict__ bhh_his,
    const float* __restrict__ Wih_int, const float* __restrict__ Whh_int,
    const float* __restrict__ bih_int, const float* __restrict__ bhh_int,
    float* __restrict__ ws)
{
    const int i = blockIdx.x * 256 + threadIdx.x;
    if (i < 4480) {
        // legacy his regions (harmless) -- keep indices stable
        if (i < 256) {
            const int r = i >> 1;
            const float s = (r >= 64 && r < 96) ? -TWOLOG2E : -LOG2E;
            ws[i] = Wih_his[i] * s;
        } else if (i < 384) {
            const int r = i - 256;
            const float s = (r >= 64 && r < 96) ? -TWOLOG2E : -LOG2E;
            ws[i] = (bih_his[r] + bhh_his[r]) * s;
        } else {
            const int e = i - 384, r = e >> 5;
            const float s = (r >= 64 && r < 96) ? -TWOLOG2E : -LOG2E;
            ws[i] = Whh_his[e] * s;
        }
    } else if (i < 4544) {              // intX
        const int e = i - 4480, r = e >> 1;
        const float s = (r >= 16 && r < 24) ? -TWOLOG2E : -LOG2E;
        ws[i] = Wih_int[e] * s;
    } else if (i < 4576) {              // intB
        const int r = i - 4544;
        const float s = (r >= 16 && r < 24) ? -TWOLOG2E : -LOG2E;
        ws[i] = (bih_int[r] + bhh_int[r]) * s;
    } else if (i < 4832) {              // intW
        const int e = i - 4576, r = e >> 3;
        const float s = (r >= 16 && r < 24) ? -TWOLOG2E : -LOG2E;
        ws[i] = Whh_int[e] * s;
    } else if (i < 4960) {              // hisBP (permuted bias, fp32)
        const int p = i - 4832;
        const int T = p >> 4, n = p & 15;
        const int gi = T >> 1, u = 2 * n + (T & 1);
        const int r = gi * 32 + u;
        const float s = (gi == 2) ? -TWOLOG2E : -LOG2E;
        ws[5120 + p] = (bih_his[r] + bhh_his[r]) * s;
    } else if (i < 5216) {              // hisXP (permuted Wih, fp32)
        const int e = i - 4960;
        const int p = e >> 1, comp = e & 1;
        const int T = p >> 4, n = p & 15;
        const int gi = T >> 1, u = 2 * n + (T & 1);
        const int r = gi * 32 + u;
        const float s = (gi == 2) ? -TWOLOG2E : -LOG2E;
        ws[5376 + e] = Wih_his[r * 2 + comp] * s;
    } else if (i < 9312) {              // hisWH (permuted Whh, fp16)
        const int e = i - 5216;
        const int p = e >> 5, k = e & 31;
        const int T = p >> 4, n = p & 15;
        const int gi = T >> 1, u = 2 * n + (T & 1);
        const int r = gi * 32 + u;
        const float s = (gi == 2) ? -TWOLOG2E : -LOG2E;
        reinterpret_cast<unsigned short*>(ws)[11776 + e] =
            f2h(Whh_his[r * 32 + k] * s);
    }
}

// ---------- int LSTM: 8 chains per wave, unit-per-lane (R11, verified) ----
__global__ __launch_bounds__(64) void int_kernel(
    const float* __restrict__ inp, const float* __restrict__ ws,
    const float* __restrict__ W_out, float* __restrict__ eInt)
{
    __shared__ __align__(16) float ib[2][8][8];

    const int lane = threadIdx.x;
    const int W    = blockIdx.x;
    const int t    = W >> 4;
    const int g    = lane >> 3;
    const int u    = lane & 7;
    const int b    = ((W & 15) << 3) | g;
    const int nsteps = (t >= 63) ? 64 : (t + 1);
    const int tau0   = (t >= 63) ? (t - 63) : 0;

    v2f wi[4][4], wxi[4];
    float bi[4];
    {
        const v2f* wsWi = reinterpret_cast<const v2f*>(ws + 4576);
        const v2f* wsXi = reinterpret_cast<const v2f*>(ws + 4480);
#pragma unroll
        for (int q = 0; q < 4; ++q) {
            const v2f* row = wsWi + (q * 8 + u) * 4;
#pragma unroll
            for (int k = 0; k < 4; ++k) wi[q][k] = row[k];
            bi[q]  = ws[4544 + q * 8 + u];
            wxi[q] = wsXi[q * 8 + u];
        }
    }

    ib[0][g][u] = 0.f;
    float cc = 0.f, h = 0.f;

    const float* xc = inp + tau0 * 1024 + b * 8;
    float2 xv2 = *reinterpret_cast<const float2*>(xc);
    xc += 1024;

#pragma unroll 1
    for (int s = 0; s < nsteps; ++s) {
        __builtin_amdgcn_wave_barrier();
        asm volatile("s_waitcnt lgkmcnt(0)" ::: "memory");
        __builtin_amdgcn_wave_barrier();

        const int rb = s & 1, wb = rb ^ 1;
        const v4f* ip = reinterpret_cast<const v4f*>(&ib[rb][g][0]);
        const v4f i0 = ip[0], i1 = ip[1];

        float2 nx = {0.f, 0.f};
        if (s + 1 < nsteps) nx = *reinterpret_cast<const float2*>(xc);
        xc += 1024;
        const v2f xv = {xv2.x, xv2.y};

        float a[4];
#pragma unroll
        for (int q = 0; q < 4; ++q) {
            v2f acc = {bi[q], 0.f};
            pk_fma(acc, wxi[q], xv);
            pk_fma(acc, wi[q][0], loh(i0));
            pk_fma(acc, wi[q][1], hih(i0));
            pk_fma(acc, wi[q][2], loh(i1));
            pk_fma(acc, wi[q][3], hih(i1));
            a[q] = acc.x + acc.y;
        }
        const float si = frcp(1.f + fexp2(a[0]));
        const float sf = frcp(1.f + fexp2(a[1]));
        const float tg = fmaf(2.f, frcp(1.f + fexp2(a[2])), -1.f);
        const float so = frcp(1.f + fexp2(a[3]));
        cc = fmaf(sf, cc, si * tg);
        h = so * fmaf(-2.f, frcp(1.f + fexp2(TWOLOG2E * cc)), 1.f);
        ib[wb][g][u] = h;

        xv2 = nx;
    }

    float e0 = W_out[32 + u] * h;
    float e1 = W_out[72 + u] * h;
#pragma unroll
    for (int m = 4; m >= 1; m >>= 1) {
        e0 += __shfl_xor(e0, m);
        e1 += __shfl_xor(e1, m);
    }
    if (u == 0) {
        float2 o; o.x = e0; o.y = e1;
        reinterpret_cast<float2*>(eInt)[t * 128 + b] = o;
    }
}

// ---------- his LSTM: 16 chains per wave via MFMA ------------------------
__global__ __launch_bounds__(64) void his_kernel(
    const float* __restrict__ inp, const float* __restrict__ ws,
    const float* __restrict__ W_out, const float* __restrict__ b_out,
    const float* __restrict__ eInt, float* __restrict__ out)
{
    __shared__ __align__(16) unsigned short hm[2][16][40];  // fp16 h, padded

    const int lane = threadIdx.x;
    const int n    = lane & 15;
    const int quad = lane >> 4;
    const int Wd   = blockIdx.x;               // 0..2047
    const int t    = Wd >> 3;                  // uniform per wave
    const int bg   = Wd & 7;                   // chains bg*16 .. +15
    const int nsteps = (t >= 63) ? 64 : (t + 1);
    const int tau0   = (t >= 63) ? (t - 63) : 0;

    // B-frags: tile T rows p=T*16+n, k=quad*8..+7 (8 fp16 = 4 VGPRs each)
    h8v Bf[8];
    {
        const h8v* wb = reinterpret_cast<const h8v*>(
            reinterpret_cast<const unsigned short*>(ws) + 11776);
#pragma unroll
        for (int T = 0; T < 8; ++T) Bf[T] = wb[(T * 16 + n) * 4 + quad];
    }
    // C-init constants (x-part): bias, w0, w1 for row p=T*16+n
    float cb[8], cw0[8], cw1[8];
#pragma unroll
    for (int T = 0; T < 8; ++T) {
        const int p = T * 16 + n;
        cb[T]  = ws[5120 + p];
        cw0[T] = ws[5376 + 2 * p];
        cw1[T] = ws[5376 + 2 * p + 1];
    }

    // x for this lane's 4 chains (quad*4+r), n=3 slot
    const int bbase = bg * 16 + quad * 4;
    const float* xp = inp + tau0 * 1024 + bbase * 8 + 6;
    float2 xc[4];
#pragma unroll
    for (int r = 0; r < 4; ++r)
        xc[r] = *reinterpret_cast<const float2*>(xp + r * 8);
    xp += 1024;

    h8v Af = {};              // h = 0
    float cs[4][2] = {};      // cell state [chain-reg][unit-pair]
    float h0[4] = {}, h1[4] = {};

#pragma unroll 1
    for (int s = 0; s < nsteps; ++s) {
        float2 xn[4];
        if (s + 1 < nsteps) {               // wave-uniform branch
#pragma unroll
            for (int r = 0; r < 4; ++r)
                xn[r] = *reinterpret_cast<const float2*>(xp + r * 8);
        } else {
#pragma unroll
            for (int r = 0; r < 4; ++r) xn[r] = make_float2(0.f, 0.f);
        }
        xp += 1024;

        // 8 MFMAs: D[T] = H @ WhhP_T + (Wih x + b)
        v4f D[8];
#pragma unroll
        for (int T = 0; T < 8; ++T) {
            v4f C;
#pragma unroll
            for (int r = 0; r < 4; ++r)
                C[r] = fmaf(cw1[T], xc[r].y, fmaf(cw0[T], xc[r].x, cb[T]));
            D[T] = __builtin_amdgcn_mfma_f32_16x16x32_f16(Af, Bf[T], C, 0, 0, 0);
        }

        // lane-local activations: 4 chains x units {2n, 2n+1}
        // tiles: 0,1=i  2,3=f  4,5=g  6,7=o  (even tile -> unit 2n)
#pragma unroll
        for (int r = 0; r < 4; ++r) {
            {
                const float si = frcp(1.f + fexp2(D[0][r]));
                const float sf = frcp(1.f + fexp2(D[2][r]));
                const float tg = fmaf(2.f, frcp(1.f + fexp2(D[4][r])), -1.f);
                const float so = frcp(1.f + fexp2(D[6][r]));
                const float cn = fmaf(sf, cs[r][0], si * tg);
                cs[r][0] = cn;
                h0[r] = so * fmaf(-2.f, frcp(1.f + fexp2(TWOLOG2E * cn)), 1.f);
            }
            {
                const float si = frcp(1.f + fexp2(D[1][r]));
                const float sf = frcp(1.f + fexp2(D[3][r]));
                const float tg = fmaf(2.f, frcp(1.f + fexp2(D[5][r])), -1.f);
                const float so = frcp(1.f + fexp2(D[7][r]));
                const float cn = fmaf(sf, cs[r][1], si * tg);
                cs[r][1] = cn;
                h1[r] = so * fmaf(-2.f, frcp(1.f + fexp2(TWOLOG2E * cn)), 1.f);
            }
        }

        // transpose h back to A-layout via wave-private LDS (skip last step)
        if (s + 1 < nsteps) {
            const int bf = s & 1;
#pragma unroll
            for (int r = 0; r < 4; ++r) {
                const unsigned pk =
                    ((unsigned)f2h(h1[r]) << 16) | f2h(h0[r]);
                *reinterpret_cast<unsigned*>(&hm[bf][quad * 4 + r][2 * n]) = pk;
            }
            __builtin_amdgcn_wave_barrier();
            asm volatile("s_waitcnt lgkmcnt(0)" ::: "memory");
            __builtin_amdgcn_wave_barrier();
            Af = *reinterpret_cast<const h8v*>(&hm[bf][n][quad * 8]);
        }

#pragma unroll
        for (int r = 0; r < 4; ++r) xc[r] = xn[r];
    }

    // ---- projection: lane has units {2n,2n+1} of 4 chains; reduce over n --
    const float wo0a = W_out[2 * n],      wo0b = W_out[2 * n + 1];
    const float wo1a = W_out[40 + 2 * n], wo1b = W_out[40 + 2 * n + 1];
    float e0[4], e1[4];
#pragma unroll
    for (int r = 0; r < 4; ++r) {
        e0[r] = fmaf(wo0b, h1[r], wo0a * h0[r]);
        e1[r] = fmaf(wo1b, h1[r], wo1a * h0[r]);
#pragma unroll
        for (int m = 1; m <= 8; m <<= 1) {
            e0[r] += __shfl_xor(e0[r], m);
            e1[r] += __shfl_xor(e1[r], m);
        }
    }
    if (n == 0) {
        const float bo0 = b_out[0], bo1 = b_out[1];
#pragma unroll
        for (int r = 0; r < 4; ++r) {
            const int chain = t * 128 + bbase + r;
            const float2 ei = reinterpret_cast<const float2*>(eInt)[chain];
            float2 o;
            o.x = e0[r] + ei.x + bo0;
            o.y = e1[r] + ei.y + bo1;
            reinterpret_cast<float2*>(out)[chain] = o;
        }
    }
}

extern "C" void kernel_launch(void* const* d_in, const int* in_sizes, int n_in,
                              void* d_out, int out_size, void* d_ws, size_t ws_size,
                              hipStream_t stream) {
    const float* inp     = (const float*)d_in[0];
    const float* Wih_his = (const float*)d_in[1];
    const float* Whh_his = (const float*)d_in[2];
    const float* bih_his = (const float*)d_in[3];
    const float* bhh_his = (const float*)d_in[4];
    const float* Wih_int = (const float*)d_in[5];
    const float* Whh_int = (const float*)d_in[6];
    const float* bih_int = (const float*)d_in[7];
    const float* bhh_int = (const float*)d_in[8];
    const float* W_out   = (const float*)d_in[9];
    const float* b_out   = (const float*)d_in[10];
    float* out  = (float*)d_out;
    float* ws   = (float*)d_ws;
    float* eInt = ws + 8192;

    // pre-pass: prescale + permute weights (incl. fp16 Whh for MFMA B-frags)
    prep_kernel<<<dim3(37), dim3(256), 0, stream>>>(
        Wih_his, Whh_his, bih_his, bhh_his,
        Wih_int, Whh_int, bih_int, bhh_int, ws);

    // int LSTM: 4096 waves, 8 chains each -> eInt contributions
    int_kernel<<<dim3(4096), dim3(64), 0, stream>>>(inp, ws, W_out, eInt);

    // his LSTM: 2048 waves, 16 chains each, 8 MFMAs per step
    his_kernel<<<dim3(2048), dim3(64), 0, stream>>>(
        inp, ws, W_out, b_out, eInt, out);
}